// Round 3
// baseline (601.804 us; speedup 1.0000x reference)
//
#include <hip/hip_runtime.h>
#include <hip/hip_bf16.h>
#include <math.h>

// ---------------------------------------------------------------------------
// GCN: 4 x [h = tanh(Dis (A+I) Dis (x W) + b)], then h @ W_out + b_out
// N=100k nodes, E=1M edges, D=64, D_out=16, all fp32.
// Pre-pass: CSR-by-dst built via bucket partition (bank write-amp fix).
// Per layer: gemm (scalar-broadcast x, W in VGPRs) -> agg (unroll-8 gathers).
// ---------------------------------------------------------------------------

#define NBSHIFT 9   // bucket = dst >> 9  (512 nodes/bucket)

__device__ __forceinline__ float tanh_fast(float x) {
    float e = __expf(2.0f * x);
    return 1.0f - 2.0f / (e + 1.0f);
}

// ---- degree count ----------------------------------------------------------
__global__ void __launch_bounds__(256) deg_kernel(const int* __restrict__ dst,
                                                  int* __restrict__ deg, int E) {
    int i = blockIdx.x * 256 + threadIdx.x;
    if (i < E) atomicAdd(&deg[dst[i]], 1);
}

// ---- dis = rsqrt(deg + 1) --------------------------------------------------
__global__ void __launch_bounds__(256) dis_kernel(const int* __restrict__ deg,
                                                  float* __restrict__ dis, int n) {
    int i = blockIdx.x * 256 + threadIdx.x;
    if (i < n) dis[i] = rsqrtf((float)deg[i] + 1.0f);
}

// ---- generic 3-phase exclusive scan ----------------------------------------
__global__ void __launch_bounds__(1024) scan1_kernel(const int* __restrict__ in,
                                                     int* __restrict__ out,
                                                     int* __restrict__ csum, int n) {
    __shared__ int s[1024];
    int t = threadIdx.x;
    int i = blockIdx.x * 1024 + t;
    int v = (i < n) ? in[i] : 0;
    s[t] = v;
    __syncthreads();
    #pragma unroll
    for (int o = 1; o < 1024; o <<= 1) {
        int a = 0;
        if (t >= o) a = s[t - o];
        __syncthreads();
        if (t >= o) s[t] += a;
        __syncthreads();
    }
    if (i < n) out[i] = s[t] - v;          // exclusive
    if (t == 1023) csum[blockIdx.x] = s[1023];
}

__global__ void __launch_bounds__(1024) scan2_kernel(int* __restrict__ csum, int nc) {
    __shared__ int s[1024];
    int t = threadIdx.x;
    int v = (t < nc) ? csum[t] : 0;
    s[t] = v;
    __syncthreads();
    #pragma unroll
    for (int o = 1; o < 1024; o <<= 1) {
        int a = 0;
        if (t >= o) a = s[t - o];
        __syncthreads();
        if (t >= o) s[t] += a;
        __syncthreads();
    }
    if (t < nc) csum[t] = s[t] - v;        // exclusive
}

__global__ void __launch_bounds__(1024) scan3_kernel(int* __restrict__ out,
                                                     const int* __restrict__ csum,
                                                     int n, int total) {
    int i = blockIdx.x * 1024 + threadIdx.x;
    if (i < n) out[i] += csum[blockIdx.x];
    if (i == 0) out[n] = total;            // sentinel
}

// ---- bucket histogram: hist[b * nblocks + blk] -----------------------------
__global__ void __launch_bounds__(256) hist_kernel(const int* __restrict__ dst,
                                                   int* __restrict__ hist,
                                                   int E, int NB, int nblocks) {
    __shared__ int lh[256];
    int t = threadIdx.x;
    lh[t] = 0;
    __syncthreads();
    int base = blockIdx.x * 4096;
    int end = base + 4096; if (end > E) end = E;
    for (int i = base + t; i < end; i += 256)
        atomicAdd(&lh[dst[i] >> NBSHIFT], 1);
    __syncthreads();
    if (t < NB) hist[t * nblocks + blockIdx.x] = lh[t];
}

// ---- partition edges into bucket-major staging -----------------------------
__global__ void __launch_bounds__(256) part_kernel(const int* __restrict__ src,
                                                   const int* __restrict__ dst,
                                                   const int* __restrict__ phist,
                                                   unsigned long long* __restrict__ staged,
                                                   int E, int NB, int nblocks) {
    __shared__ int lcur[256];
    int t = threadIdx.x;
    if (t < NB) lcur[t] = phist[t * nblocks + blockIdx.x];
    __syncthreads();
    int base = blockIdx.x * 4096;
    int end = base + 4096; if (end > E) end = E;
    for (int i = base + t; i < end; i += 256) {
        int d = dst[i];
        int b = d >> NBSHIFT;
        int pos = atomicAdd(&lcur[b], 1);
        staged[pos] = ((unsigned long long)(unsigned)d << 32) | (unsigned)src[i];
    }
}

// ---- per-bucket local CSR fill (L2-resident windows) -----------------------
__global__ void __launch_bounds__(256) fill2_kernel(const unsigned long long* __restrict__ staged,
                                                    const int* __restrict__ phist,
                                                    const int* __restrict__ off,
                                                    int* __restrict__ cursor,
                                                    int* __restrict__ srcl,
                                                    int nblocks) {
    int b = blockIdx.x;
    int r0 = phist[b * nblocks];
    int r1 = phist[(b + 1) * nblocks];     // sentinel covers last bucket
    for (int i = r0 + threadIdx.x; i < r1; i += 256) {
        unsigned long long rec = staged[i];
        int d = (int)(rec >> 32);
        int s = (int)(rec & 0xffffffffu);
        int pos = atomicAdd(&cursor[d], 1);
        srcl[off[d] + pos] = s;
    }
}

// ---- g[n][d] = dis[n] * sum_k x[n][k] * W[k][d] ----------------------------
// One node per wave iteration; x row via wave-uniform (scalar) loads;
// W column in 64 VGPRs per lane. No LDS.
__global__ void __launch_bounds__(256) gemm_g_kernel(const float* __restrict__ x,
                                                     const float* __restrict__ W,
                                                     const float* __restrict__ dis,
                                                     float* __restrict__ g, int n) {
    int t = threadIdx.x;
    int lane = t & 63;
    int wave = __builtin_amdgcn_readfirstlane(t >> 6);
    float Wr[64];
    #pragma unroll
    for (int k = 0; k < 64; ++k) Wr[k] = W[k * 64 + lane];
    int wbase = (blockIdx.x * 4 + wave) * 16;
    for (int i = 0; i < 16; ++i) {
        int node = wbase + i;
        if (node >= n) return;
        const float4* xr = (const float4*)(x + ((size_t)node << 6));
        float a0 = 0.f, a1 = 0.f, a2 = 0.f, a3 = 0.f;
        #pragma unroll
        for (int k4 = 0; k4 < 16; ++k4) {
            float4 xv = xr[k4];             // uniform -> s_load
            a0 = fmaf(xv.x, Wr[4 * k4 + 0], a0);
            a1 = fmaf(xv.y, Wr[4 * k4 + 1], a1);
            a2 = fmaf(xv.z, Wr[4 * k4 + 2], a2);
            a3 = fmaf(xv.w, Wr[4 * k4 + 3], a3);
        }
        g[((size_t)node << 6) + lane] = dis[node] * ((a0 + a1) + (a2 + a3));
    }
}

// ---- h[n][d] = tanh(dis[n]*(g[n][d] + sum_in g[src][d]) + b[d]) ------------
// 4 nodes/wave (16-lane quarters, float4/lane), unroll-8 gathers for MLP.
__global__ void __launch_bounds__(256) agg_kernel(const float* __restrict__ g,
                                                  const float* __restrict__ dis,
                                                  const int* __restrict__ off,
                                                  const int* __restrict__ srcl,
                                                  const float* __restrict__ bias,
                                                  float* __restrict__ out, int n) {
    int t = threadIdx.x;
    int lane = t & 63;
    int q = lane >> 4;
    int r = lane & 15;
    int node = (blockIdx.x << 4) + ((t >> 6) << 2) + q;
    if (node >= n) return;

    const float4* gv = (const float4*)g;
    float4 s = gv[node * 16 + r];
    int e = off[node], e1 = off[node + 1];
    while (e1 - e >= 8) {
        int i0 = srcl[e + 0], i1 = srcl[e + 1], i2 = srcl[e + 2], i3 = srcl[e + 3];
        int i4 = srcl[e + 4], i5 = srcl[e + 5], i6 = srcl[e + 6], i7 = srcl[e + 7];
        float4 a0 = gv[i0 * 16 + r], a1 = gv[i1 * 16 + r];
        float4 a2 = gv[i2 * 16 + r], a3 = gv[i3 * 16 + r];
        float4 a4 = gv[i4 * 16 + r], a5 = gv[i5 * 16 + r];
        float4 a6 = gv[i6 * 16 + r], a7 = gv[i7 * 16 + r];
        s.x += ((a0.x + a1.x) + (a2.x + a3.x)) + ((a4.x + a5.x) + (a6.x + a7.x));
        s.y += ((a0.y + a1.y) + (a2.y + a3.y)) + ((a4.y + a5.y) + (a6.y + a7.y));
        s.z += ((a0.z + a1.z) + (a2.z + a3.z)) + ((a4.z + a5.z) + (a6.z + a7.z));
        s.w += ((a0.w + a1.w) + (a2.w + a3.w)) + ((a4.w + a5.w) + (a6.w + a7.w));
        e += 8;
    }
    if (e1 - e >= 4) {
        int i0 = srcl[e + 0], i1 = srcl[e + 1], i2 = srcl[e + 2], i3 = srcl[e + 3];
        float4 a0 = gv[i0 * 16 + r], a1 = gv[i1 * 16 + r];
        float4 a2 = gv[i2 * 16 + r], a3 = gv[i3 * 16 + r];
        s.x += (a0.x + a1.x) + (a2.x + a3.x);
        s.y += (a0.y + a1.y) + (a2.y + a3.y);
        s.z += (a0.z + a1.z) + (a2.z + a3.z);
        s.w += (a0.w + a1.w) + (a2.w + a3.w);
        e += 4;
    }
    while (e < e1) {
        float4 a = gv[srcl[e] * 16 + r];
        s.x += a.x; s.y += a.y; s.z += a.z; s.w += a.w;
        ++e;
    }
    float dn = dis[node];
    float4 b = ((const float4*)bias)[r];
    float4 h;
    h.x = tanh_fast(fmaf(dn, s.x, b.x));
    h.y = tanh_fast(fmaf(dn, s.y, b.y));
    h.z = tanh_fast(fmaf(dn, s.z, b.z));
    h.w = tanh_fast(fmaf(dn, s.w, b.w));
    ((float4*)out)[node * 16 + r] = h;
}

// ---- final: out[n][j] = sum_k h[n][k]*Wo[k][j] + bo[j], j<16 ---------------
__global__ void __launch_bounds__(256) final_kernel(const float* __restrict__ h,
                                                    const float* __restrict__ Wo,
                                                    const float* __restrict__ bo,
                                                    float* __restrict__ out, int n) {
    __shared__ float Wl[1024];
    __shared__ float bl[16];
    __shared__ float hs[16 * 68];
    int t = threadIdx.x;
    for (int i = t; i < 1024; i += 256) Wl[i] = Wo[i];
    if (t < 16) bl[t] = bo[t];
    int nodeBase = blockIdx.x * 16;
    for (int i = t; i < 1024; i += 256) {
        int nn = i >> 6, kk = i & 63;
        if (nodeBase + nn < n) hs[nn * 68 + kk] = h[(nodeBase + nn) * 64 + kk];
    }
    __syncthreads();
    int nsub = t >> 4;
    int j = t & 15;
    int node = nodeBase + nsub;
    if (node >= n) return;
    const float* hr = hs + nsub * 68;
    float acc = bl[j];
    #pragma unroll
    for (int k = 0; k < 64; ++k) acc = fmaf(hr[k], Wl[k * 16 + j], acc);
    out[node * 16 + j] = acc;
}

// ---------------------------------------------------------------------------
extern "C" void kernel_launch(void* const* d_in, const int* in_sizes, int n_in,
                              void* d_out, int out_size, void* d_ws, size_t ws_size,
                              hipStream_t stream) {
    const float* x     = (const float*)d_in[0];
    const int*   ei    = (const int*)d_in[1];   // (2, E) int32
    const float* W[4]  = {(const float*)d_in[2], (const float*)d_in[4],
                          (const float*)d_in[6], (const float*)d_in[8]};
    const float* B[4]  = {(const float*)d_in[3], (const float*)d_in[5],
                          (const float*)d_in[7], (const float*)d_in[9]};
    const float* Wo    = (const float*)d_in[10];
    const float* bo    = (const float*)d_in[11];
    float* out         = (float*)d_out;

    const int N = in_sizes[0] / 64;
    const int E = in_sizes[1] / 2;
    const int* srcp = ei;
    const int* dstp = ei + E;

    const int NB       = (N + (1 << NBSHIFT) - 1) >> NBSHIFT;  // 196 buckets
    const int nblocksP = (E + 4095) / 4096;                    // 245
    const int NH       = NB * nblocksP;

    char* w = (char*)d_ws;
    size_t o = 0;
    auto alloc = [&](size_t bytes) { void* p = w + o; o = (o + bytes + 255) & ~(size_t)255; return p; };
    float* dis    = (float*)alloc((size_t)N * 4);
    int*   degi   = (int*)  alloc((size_t)N * 4);
    int*   off    = (int*)  alloc((size_t)(N + 1) * 4);
    int*   cursor = (int*)  alloc((size_t)N * 4);
    int*   csum   = (int*)  alloc(4096);
    int*   srcl   = (int*)  alloc((size_t)E * 4);
    int*   hist   = (int*)  alloc((size_t)NH * 4);
    int*   phist  = (int*)  alloc((size_t)(NH + 1) * 4);
    float* bufA   = (float*)alloc((size_t)N * 64 * 4);
    float* bufB   = (float*)alloc((size_t)N * 64 * 4);
    unsigned long long* staged = (unsigned long long*)bufA;    // reuse (8MB < 25.6MB)

    hipMemsetAsync(degi,   0, (size_t)N * 4, stream);
    hipMemsetAsync(cursor, 0, (size_t)N * 4, stream);

    int ge  = (E + 255) / 256;
    int gn  = (N + 255) / 256;
    int nchN = (N + 1023) / 1024;
    int nchH = (NH + 1023) / 1024;

    deg_kernel<<<ge, 256, 0, stream>>>(dstp, degi, E);
    dis_kernel<<<gn, 256, 0, stream>>>(degi, dis, N);
    // CSR offsets
    scan1_kernel<<<nchN, 1024, 0, stream>>>(degi, off, csum, N);
    scan2_kernel<<<1, 1024, 0, stream>>>(csum, nchN);
    scan3_kernel<<<nchN, 1024, 0, stream>>>(off, csum, N, E);
    // bucket partition
    hist_kernel<<<nblocksP, 256, 0, stream>>>(dstp, hist, E, NB, nblocksP);
    scan1_kernel<<<nchH, 1024, 0, stream>>>(hist, phist, csum, NH);
    scan2_kernel<<<1, 1024, 0, stream>>>(csum, nchH);
    scan3_kernel<<<nchH, 1024, 0, stream>>>(phist, csum, NH, E);
    part_kernel<<<nblocksP, 256, 0, stream>>>(srcp, dstp, phist, staged, E, NB, nblocksP);
    fill2_kernel<<<NB, 256, 0, stream>>>(staged, phist, off, cursor, srcl, nblocksP);

    int gemm_blocks = (N + 63) / 64;
    int agg_blocks  = (N + 15) / 16;

    const float* cur = x;
    for (int l = 0; l < 4; ++l) {
        gemm_g_kernel<<<gemm_blocks, 256, 0, stream>>>(cur, W[l], dis, bufA, N);
        agg_kernel<<<agg_blocks, 256, 0, stream>>>(bufA, dis, off, srcl, B[l], bufB, N);
        cur = bufB;
    }
    final_kernel<<<(N + 15) / 16, 256, 0, stream>>>(bufB, Wo, bo, out, N);
}

// Round 6
// 426.041 us; speedup vs baseline: 1.4125x; 1.4125x over previous
//
#include <hip/hip_runtime.h>
#include <hip/hip_bf16.h>
#include <math.h>

// ---------------------------------------------------------------------------
// GCN: 4 x [h = tanh(Dis (A+I) Dis (x W) + b)], then h @ W_out + b_out
// N=100k nodes, E=1M edges, D=64, D_out=16, all fp32.
// gemm via MFMA bf16 3-term split (AhBh + AlBh + AhBl), fp32 accumulate.
// CSR-by-dst built via bucket partition; agg = unroll-8 row gathers.
// ---------------------------------------------------------------------------

#define NBSHIFT 9   // bucket = dst >> 9  (512 nodes/bucket)

typedef __attribute__((ext_vector_type(8))) short short8;
typedef __attribute__((ext_vector_type(4))) float f32x4;

__device__ __forceinline__ float tanh_fast(float x) {
    float e = __expf(2.0f * x);
    return 1.0f - 2.0f / (e + 1.0f);
}
__device__ __forceinline__ unsigned short f2bf(float f) {   // RNE float->bf16
    unsigned u = __float_as_uint(f);
    return (unsigned short)((u + 0x7fff + ((u >> 16) & 1)) >> 16);
}
__device__ __forceinline__ float bf2f(unsigned short h) {
    return __uint_as_float((unsigned)h << 16);
}

// ---- degree count ----------------------------------------------------------
__global__ void __launch_bounds__(256) deg_kernel(const int* __restrict__ dst,
                                                  int* __restrict__ deg, int E) {
    int i = blockIdx.x * 256 + threadIdx.x;
    if (i < E) atomicAdd(&deg[dst[i]], 1);
}

// ---- dis = rsqrt(deg + 1) --------------------------------------------------
__global__ void __launch_bounds__(256) dis_kernel(const int* __restrict__ deg,
                                                  float* __restrict__ dis, int n) {
    int i = blockIdx.x * 256 + threadIdx.x;
    if (i < n) dis[i] = rsqrtf((float)deg[i] + 1.0f);
}

// ---- generic 3-phase exclusive scan ----------------------------------------
__global__ void __launch_bounds__(1024) scan1_kernel(const int* __restrict__ in,
                                                     int* __restrict__ out,
                                                     int* __restrict__ csum, int n) {
    __shared__ int s[1024];
    int t = threadIdx.x;
    int i = blockIdx.x * 1024 + t;
    int v = (i < n) ? in[i] : 0;
    s[t] = v;
    __syncthreads();
    #pragma unroll
    for (int o = 1; o < 1024; o <<= 1) {
        int a = 0;
        if (t >= o) a = s[t - o];
        __syncthreads();
        if (t >= o) s[t] += a;
        __syncthreads();
    }
    if (i < n) out[i] = s[t] - v;          // exclusive
    if (t == 1023) csum[blockIdx.x] = s[1023];
}

__global__ void __launch_bounds__(1024) scan2_kernel(int* __restrict__ csum, int nc) {
    __shared__ int s[1024];
    int t = threadIdx.x;
    int v = (t < nc) ? csum[t] : 0;
    s[t] = v;
    __syncthreads();
    #pragma unroll
    for (int o = 1; o < 1024; o <<= 1) {
        int a = 0;
        if (t >= o) a = s[t - o];
        __syncthreads();
        if (t >= o) s[t] += a;
        __syncthreads();
    }
    if (t < nc) csum[t] = s[t] - v;        // exclusive
}

__global__ void __launch_bounds__(1024) scan3_kernel(int* __restrict__ out,
                                                     const int* __restrict__ csum,
                                                     int n, int total) {
    int i = blockIdx.x * 1024 + threadIdx.x;
    if (i < n) out[i] += csum[blockIdx.x];
    if (i == 0) out[n] = total;            // sentinel
}

// ---- bucket histogram ------------------------------------------------------
__global__ void __launch_bounds__(256) hist_kernel(const int* __restrict__ dst,
                                                   int* __restrict__ hist,
                                                   int E, int NB, int nblocks) {
    __shared__ int lh[256];
    int t = threadIdx.x;
    lh[t] = 0;
    __syncthreads();
    int base = blockIdx.x * 4096;
    int end = base + 4096; if (end > E) end = E;
    for (int i = base + t; i < end; i += 256)
        atomicAdd(&lh[dst[i] >> NBSHIFT], 1);
    __syncthreads();
    if (t < NB) hist[t * nblocks + blockIdx.x] = lh[t];
}

// ---- partition edges into bucket-major staging -----------------------------
__global__ void __launch_bounds__(256) part_kernel(const int* __restrict__ src,
                                                   const int* __restrict__ dst,
                                                   const int* __restrict__ phist,
                                                   unsigned long long* __restrict__ staged,
                                                   int E, int NB, int nblocks) {
    __shared__ int lcur[256];
    int t = threadIdx.x;
    if (t < NB) lcur[t] = phist[t * nblocks + blockIdx.x];
    __syncthreads();
    int base = blockIdx.x * 4096;
    int end = base + 4096; if (end > E) end = E;
    for (int i = base + t; i < end; i += 256) {
        int d = dst[i];
        int b = d >> NBSHIFT;
        int pos = atomicAdd(&lcur[b], 1);
        staged[pos] = ((unsigned long long)(unsigned)d << 32) | (unsigned)src[i];
    }
}

// ---- per-bucket local CSR fill ---------------------------------------------
__global__ void __launch_bounds__(256) fill2_kernel(const unsigned long long* __restrict__ staged,
                                                    const int* __restrict__ phist,
                                                    const int* __restrict__ off,
                                                    int* __restrict__ cursor,
                                                    int* __restrict__ srcl,
                                                    int nblocks) {
    int b = blockIdx.x;
    int r0 = phist[b * nblocks];
    int r1 = phist[(b + 1) * nblocks];
    for (int i = r0 + threadIdx.x; i < r1; i += 256) {
        unsigned long long rec = staged[i];
        int d = (int)(rec >> 32);
        int s = (int)(rec & 0xffffffffu);
        int pos = atomicAdd(&cursor[d], 1);
        srcl[off[d] + pos] = s;
    }
}

// ---- W fragment prep: bf16 hi/lo frags arranged frag-major -----------------
// wf[l][ct][kk][hl] is a 1KB block: 64 lanes x short8 (lane-consecutive 16B).
// Frag element e of lane l: W[kk*32 + (l>>4)*8 + e][ct*16 + (l&15)].
__global__ void __launch_bounds__(256) wprep_kernel(const float* __restrict__ W0,
                                                    const float* __restrict__ W1,
                                                    const float* __restrict__ W2,
                                                    const float* __restrict__ W3,
                                                    short* __restrict__ wf) {
    const float* Ws[4] = {W0, W1, W2, W3};
    int l = blockIdx.x;
    const float* Wg = Ws[l];
    int t = threadIdx.x;
    int lane = t & 63;
    int ct = t >> 6;
    #pragma unroll
    for (int kk = 0; kk < 2; ++kk) {
        #pragma unroll
        for (int e = 0; e < 8; ++e) {
            int k = kk * 32 + (lane >> 4) * 8 + e;
            int c = ct * 16 + (lane & 15);
            float w = Wg[k * 64 + c];
            unsigned short hi = f2bf(w);
            unsigned short lo = f2bf(w - bf2f(hi));
            size_t b = ((size_t)l * 4 + ct) * 2 + kk;
            wf[((b * 2 + 0) * 64 + lane) * 8 + e] = (short)hi;
            wf[((b * 2 + 1) * 64 + lane) * 8 + e] = (short)lo;
        }
    }
}

// ---- MFMA gemm: g[n][d] = dis[n] * sum_k in[n][k] * W[k][d] ----------------
// One 16-node tile per wave; fp32 input split to bf16 hi/lo in-reg;
// 24 x mfma_f32_16x16x32_bf16 per tile (3-term split, 4 col-tiles, 2 k-halves).
#define SPLIT8(vA, vB, H, L) { \
    float _f[8] = {vA.x, vA.y, vA.z, vA.w, vB.x, vB.y, vB.z, vB.w}; \
    _Pragma("unroll") \
    for (int _e = 0; _e < 8; ++_e) { \
        unsigned short _h = f2bf(_f[_e]); \
        H[_e] = (short)_h; \
        L[_e] = (short)f2bf(_f[_e] - bf2f(_h)); \
    } }

__global__ void __launch_bounds__(256) gemm2_kernel(const float* __restrict__ in,
                                                    const short* __restrict__ wf,
                                                    const float* __restrict__ dis,
                                                    float* __restrict__ g, int n) {
    int t = threadIdx.x;
    int lane = t & 63;
    int wave = t >> 6;
    int c = lane & 15;
    int g4 = lane >> 4;

    // B fragments (L1-resident after first wave of the CU)
    short8 Bh[4][2], Bl[4][2];
    #pragma unroll
    for (int ct = 0; ct < 4; ++ct) {
        #pragma unroll
        for (int kk = 0; kk < 2; ++kk) {
            int b = (ct * 2 + kk) * 2;
            Bh[ct][kk] = *(const short8*)(wf + ((size_t)(b + 0) * 64 + lane) * 8);
            Bl[ct][kk] = *(const short8*)(wf + ((size_t)(b + 1) * 64 + lane) * 8);
        }
    }

    int tile = blockIdx.x * 4 + wave;
    int base = tile * 16;
    if (base >= n) return;

    // A row: row = base + (lane&15), k-offset = g4*8 (+32 for kk=1)
    const float4* ap = (const float4*)(in + (size_t)(base + c) * 64 + g4 * 8);
    float4 v00 = ap[0], v01 = ap[1];     // kk=0: e0..3, e4..7
    float4 v10 = ap[8], v11 = ap[9];     // kk=1 (+32 floats)

    short8 Ah0, Al0, Ah1, Al1;
    SPLIT8(v00, v01, Ah0, Al0);
    SPLIT8(v10, v11, Ah1, Al1);

    f32x4 acc[4];
    #pragma unroll
    for (int ct = 0; ct < 4; ++ct) {
        f32x4 a = {0.f, 0.f, 0.f, 0.f};
        a = __builtin_amdgcn_mfma_f32_16x16x32_bf16(Ah0, Bh[ct][0], a, 0, 0, 0);
        a = __builtin_amdgcn_mfma_f32_16x16x32_bf16(Ah1, Bh[ct][1], a, 0, 0, 0);
        a = __builtin_amdgcn_mfma_f32_16x16x32_bf16(Al0, Bh[ct][0], a, 0, 0, 0);
        a = __builtin_amdgcn_mfma_f32_16x16x32_bf16(Al1, Bh[ct][1], a, 0, 0, 0);
        a = __builtin_amdgcn_mfma_f32_16x16x32_bf16(Ah0, Bl[ct][0], a, 0, 0, 0);
        a = __builtin_amdgcn_mfma_f32_16x16x32_bf16(Ah1, Bl[ct][1], a, 0, 0, 0);
        acc[ct] = a;
    }

    // D: row = base + g4*4 + r, col = ct*16 + c
    f32x4 dvv = *(const f32x4*)(dis + base + g4 * 4);
    #pragma unroll
    for (int ct = 0; ct < 4; ++ct) {
        #pragma unroll
        for (int r = 0; r < 4; ++r) {
            g[(size_t)(base + g4 * 4 + r) * 64 + ct * 16 + c] = dvv[r] * acc[ct][r];
        }
    }
}

// ---- h[n][d] = tanh(dis[n]*(g[n][d] + sum_in g[src][d]) + b[d]) ------------
__global__ void __launch_bounds__(256) agg_kernel(const float* __restrict__ g,
                                                  const float* __restrict__ dis,
                                                  const int* __restrict__ off,
                                                  const int* __restrict__ srcl,
                                                  const float* __restrict__ bias,
                                                  float* __restrict__ out, int n) {
    int t = threadIdx.x;
    int lane = t & 63;
    int q = lane >> 4;
    int r = lane & 15;
    int node = (blockIdx.x << 4) + ((t >> 6) << 2) + q;
    if (node >= n) return;

    const float4* gv = (const float4*)g;
    float4 s = gv[node * 16 + r];
    int e = off[node], e1 = off[node + 1];
    while (e1 - e >= 8) {
        int i0 = srcl[e + 0], i1 = srcl[e + 1], i2 = srcl[e + 2], i3 = srcl[e + 3];
        int i4 = srcl[e + 4], i5 = srcl[e + 5], i6 = srcl[e + 6], i7 = srcl[e + 7];
        float4 a0 = gv[i0 * 16 + r], a1 = gv[i1 * 16 + r];
        float4 a2 = gv[i2 * 16 + r], a3 = gv[i3 * 16 + r];
        float4 a4 = gv[i4 * 16 + r], a5 = gv[i5 * 16 + r];
        float4 a6 = gv[i6 * 16 + r], a7 = gv[i7 * 16 + r];
        s.x += ((a0.x + a1.x) + (a2.x + a3.x)) + ((a4.x + a5.x) + (a6.x + a7.x));
        s.y += ((a0.y + a1.y) + (a2.y + a3.y)) + ((a4.y + a5.y) + (a6.y + a7.y));
        s.z += ((a0.z + a1.z) + (a2.z + a3.z)) + ((a4.z + a5.z) + (a6.z + a7.z));
        s.w += ((a0.w + a1.w) + (a2.w + a3.w)) + ((a4.w + a5.w) + (a6.w + a7.w));
        e += 8;
    }
    if (e1 - e >= 4) {
        int i0 = srcl[e + 0], i1 = srcl[e + 1], i2 = srcl[e + 2], i3 = srcl[e + 3];
        float4 a0 = gv[i0 * 16 + r], a1 = gv[i1 * 16 + r];
        float4 a2 = gv[i2 * 16 + r], a3 = gv[i3 * 16 + r];
        s.x += (a0.x + a1.x) + (a2.x + a3.x);
        s.y += (a0.y + a1.y) + (a2.y + a3.y);
        s.z += (a0.z + a1.z) + (a2.z + a3.z);
        s.w += (a0.w + a1.w) + (a2.w + a3.w);
        e += 4;
    }
    while (e < e1) {
        float4 a = gv[srcl[e] * 16 + r];
        s.x += a.x; s.y += a.y; s.z += a.z; s.w += a.w;
        ++e;
    }
    float dn = dis[node];
    float4 b = ((const float4*)bias)[r];
    float4 h;
    h.x = tanh_fast(fmaf(dn, s.x, b.x));
    h.y = tanh_fast(fmaf(dn, s.y, b.y));
    h.z = tanh_fast(fmaf(dn, s.z, b.z));
    h.w = tanh_fast(fmaf(dn, s.w, b.w));
    ((float4*)out)[node * 16 + r] = h;
}

// ---- final: out[n][j] = sum_k h[n][k]*Wo[k][j] + bo[j], j<16 ---------------
__global__ void __launch_bounds__(256) final_kernel(const float* __restrict__ h,
                                                    const float* __restrict__ Wo,
                                                    const float* __restrict__ bo,
                                                    float* __restrict__ out, int n) {
    __shared__ float Wl[1024];
    __shared__ float bl[16];
    __shared__ float hs[16 * 68];
    int t = threadIdx.x;
    for (int i = t; i < 1024; i += 256) Wl[i] = Wo[i];
    if (t < 16) bl[t] = bo[t];
    int nodeBase = blockIdx.x * 16;
    for (int i = t; i < 1024; i += 256) {
        int nn = i >> 6, kk = i & 63;
        if (nodeBase + nn < n) hs[nn * 68 + kk] = h[(nodeBase + nn) * 64 + kk];
    }
    __syncthreads();
    int nsub = t >> 4;
    int j = t & 15;
    int node = nodeBase + nsub;
    if (node >= n) return;
    const float* hr = hs + nsub * 68;
    float acc = bl[j];
    #pragma unroll
    for (int k = 0; k < 64; ++k) acc = fmaf(hr[k], Wl[k * 16 + j], acc);
    out[node * 16 + j] = acc;
}

// ---------------------------------------------------------------------------
extern "C" void kernel_launch(void* const* d_in, const int* in_sizes, int n_in,
                              void* d_out, int out_size, void* d_ws, size_t ws_size,
                              hipStream_t stream) {
    const float* x     = (const float*)d_in[0];
    const int*   ei    = (const int*)d_in[1];   // (2, E) int32
    const float* W[4]  = {(const float*)d_in[2], (const float*)d_in[4],
                          (const float*)d_in[6], (const float*)d_in[8]};
    const float* B[4]  = {(const float*)d_in[3], (const float*)d_in[5],
                          (const float*)d_in[7], (const float*)d_in[9]};
    const float* Wo    = (const float*)d_in[10];
    const float* bo    = (const float*)d_in[11];
    float* out         = (float*)d_out;

    const int N = in_sizes[0] / 64;
    const int E = in_sizes[1] / 2;
    const int* srcp = ei;
    const int* dstp = ei + E;

    const int NB       = (N + (1 << NBSHIFT) - 1) >> NBSHIFT;
    const int nblocksP = (E + 4095) / 4096;
    const int NH       = NB * nblocksP;

    char* w = (char*)d_ws;
    size_t o = 0;
    auto alloc = [&](size_t bytes) { void* p = w + o; o = (o + bytes + 255) & ~(size_t)255; return p; };
    float* dis    = (float*)alloc((size_t)N * 4);
    int*   degi   = (int*)  alloc((size_t)N * 4);
    int*   off    = (int*)  alloc((size_t)(N + 1) * 4);
    int*   cursor = (int*)  alloc((size_t)N * 4);
    int*   csum   = (int*)  alloc(4096);
    int*   srcl   = (int*)  alloc((size_t)E * 4);
    int*   hist   = (int*)  alloc((size_t)NH * 4);
    int*   phist  = (int*)  alloc((size_t)(NH + 1) * 4);
    short* wf     = (short*)alloc((size_t)4 * 8192 * 2);   // 4 layers x 16KB
    float* bufA   = (float*)alloc((size_t)N * 64 * 4);
    float* bufB   = (float*)alloc((size_t)N * 64 * 4);
    unsigned long long* staged = (unsigned long long*)bufA; // reuse

    hipMemsetAsync(degi,   0, (size_t)N * 4, stream);
    hipMemsetAsync(cursor, 0, (size_t)N * 4, stream);

    int ge   = (E + 255) / 256;
    int gn   = (N + 255) / 256;
    int nchN = (N + 1023) / 1024;
    int nchH = (NH + 1023) / 1024;

    wprep_kernel<<<4, 256, 0, stream>>>(W[0], W[1], W[2], W[3], wf);
    deg_kernel<<<ge, 256, 0, stream>>>(dstp, degi, E);
    dis_kernel<<<gn, 256, 0, stream>>>(degi, dis, N);
    scan1_kernel<<<nchN, 1024, 0, stream>>>(degi, off, csum, N);
    scan2_kernel<<<1, 1024, 0, stream>>>(csum, nchN);
    scan3_kernel<<<nchN, 1024, 0, stream>>>(off, csum, N, E);
    hist_kernel<<<nblocksP, 256, 0, stream>>>(dstp, hist, E, NB, nblocksP);
    scan1_kernel<<<nchH, 1024, 0, stream>>>(hist, phist, csum, NH);
    scan2_kernel<<<1, 1024, 0, stream>>>(csum, nchH);
    scan3_kernel<<<nchH, 1024, 0, stream>>>(phist, csum, NH, E);
    part_kernel<<<nblocksP, 256, 0, stream>>>(srcp, dstp, phist, staged, E, NB, nblocksP);
    fill2_kernel<<<NB, 256, 0, stream>>>(staged, phist, off, cursor, srcl, nblocksP);

    int tiles     = (N + 15) / 16;
    int g2_blocks = (tiles + 3) / 4;
    int agg_blocks = (N + 15) / 16;

    const float* cur = x;
    for (int l = 0; l < 4; ++l) {
        gemm2_kernel<<<g2_blocks, 256, 0, stream>>>(cur, wf + (size_t)l * 8192, dis, bufA, N);
        agg_kernel<<<agg_blocks, 256, 0, stream>>>(bufA, dis, off, srcl, B[l], bufB, N);
        cur = bufB;
    }
    final_kernel<<<(N + 15) / 16, 256, 0, stream>>>(bufB, Wo, bo, out, N);
}

// Round 8
// 367.485 us; speedup vs baseline: 1.6376x; 1.1593x over previous
//
#include <hip/hip_runtime.h>
#include <hip/hip_bf16.h>
#include <math.h>

// ---------------------------------------------------------------------------
// GCN: 4 x [h = tanh(Dis (A+I) Dis (x W) + b)], then h @ W_out + b_out
// N=100k nodes, E=1M edges, D=64, D_out=16, all fp32.
// Setup: bucket partition (packed u32 records) -> LDS-counted degrees ->
//        CSR fill with LDS cursors. No global atomics on hot arrays.
// Layers: gemm2 (MFMA bf16 3-term split) for layer 0, then
//         fused agg(l)+gemm(l+1) through padded LDS; last layer fuses
//         agg+final 64->16 projection.
// ---------------------------------------------------------------------------

#define NBSHIFT 9   // bucket = dst >> 9  (512 nodes/bucket)

typedef __attribute__((ext_vector_type(8))) short short8;
typedef __attribute__((ext_vector_type(4))) float f32x4;

__device__ __forceinline__ float tanh_fast(float x) {
    float e = __expf(2.0f * x);
    return 1.0f - 2.0f / (e + 1.0f);
}
__device__ __forceinline__ unsigned short f2bf(float f) {   // RNE float->bf16
    unsigned u = __float_as_uint(f);
    return (unsigned short)((u + 0x7fff + ((u >> 16) & 1)) >> 16);
}
__device__ __forceinline__ float bf2f(unsigned short h) {
    return __uint_as_float((unsigned)h << 16);
}

// ---- generic 3-phase exclusive scan ----------------------------------------
__global__ void __launch_bounds__(1024) scan1_kernel(const int* __restrict__ in,
                                                     int* __restrict__ out,
                                                     int* __restrict__ csum, int n) {
    __shared__ int s[1024];
    int t = threadIdx.x;
    int i = blockIdx.x * 1024 + t;
    int v = (i < n) ? in[i] : 0;
    s[t] = v;
    __syncthreads();
    #pragma unroll
    for (int o = 1; o < 1024; o <<= 1) {
        int a = 0;
        if (t >= o) a = s[t - o];
        __syncthreads();
        if (t >= o) s[t] += a;
        __syncthreads();
    }
    if (i < n) out[i] = s[t] - v;          // exclusive
    if (t == 1023) csum[blockIdx.x] = s[1023];
}

__global__ void __launch_bounds__(1024) scan2_kernel(int* __restrict__ csum, int nc) {
    __shared__ int s[1024];
    int t = threadIdx.x;
    int v = (t < nc) ? csum[t] : 0;
    s[t] = v;
    __syncthreads();
    #pragma unroll
    for (int o = 1; o < 1024; o <<= 1) {
        int a = 0;
        if (t >= o) a = s[t - o];
        __syncthreads();
        if (t >= o) s[t] += a;
        __syncthreads();
    }
    if (t < nc) csum[t] = s[t] - v;        // exclusive
}

__global__ void __launch_bounds__(1024) scan3_kernel(int* __restrict__ out,
                                                     const int* __restrict__ csum,
                                                     int n, int total) {
    int i = blockIdx.x * 1024 + threadIdx.x;
    if (i < n) out[i] += csum[blockIdx.x];
    if (i == 0) out[n] = total;            // sentinel
}

// ---- bucket histogram ------------------------------------------------------
__global__ void __launch_bounds__(256) hist_kernel(const int* __restrict__ dst,
                                                   int* __restrict__ hist,
                                                   int E, int NB, int nblocks) {
    __shared__ int lh[256];
    int t = threadIdx.x;
    lh[t] = 0;
    __syncthreads();
    int base = blockIdx.x * 4096;
    int end = base + 4096; if (end > E) end = E;
    for (int i = base + t; i < end; i += 256)
        atomicAdd(&lh[dst[i] >> NBSHIFT], 1);
    __syncthreads();
    if (t < NB) hist[t * nblocks + blockIdx.x] = lh[t];
}

// ---- partition edges into bucket-major staging (packed u32) ----------------
// record = (local_dst[9b] << 17) | src[17b]   (N < 131072)
__global__ void __launch_bounds__(256) part_kernel(const int* __restrict__ src,
                                                   const int* __restrict__ dst,
                                                   const int* __restrict__ phist,
                                                   unsigned* __restrict__ staged,
                                                   int E, int NB, int nblocks) {
    __shared__ int lcur[256];
    int t = threadIdx.x;
    if (t < NB) lcur[t] = phist[t * nblocks + blockIdx.x];
    __syncthreads();
    int base = blockIdx.x * 4096;
    int end = base + 4096; if (end > E) end = E;
    for (int i = base + t; i < end; i += 256) {
        int d = dst[i];
        int b = d >> NBSHIFT;
        int pos = atomicAdd(&lcur[b], 1);
        staged[pos] = ((unsigned)(d & 511) << 17) | (unsigned)src[i];
    }
}

// ---- per-bucket degree count in LDS + dis = rsqrt(deg+1) -------------------
__global__ void __launch_bounds__(256) bdeg_kernel(const unsigned* __restrict__ staged,
                                                   const int* __restrict__ phist,
                                                   int* __restrict__ deg,
                                                   float* __restrict__ dis,
                                                   int nblocks, int n) {
    __shared__ int ldeg[512];
    int b = blockIdx.x, t = threadIdx.x;
    ldeg[t] = 0; ldeg[t + 256] = 0;
    __syncthreads();
    int r0 = phist[b * nblocks];
    int r1 = phist[(b + 1) * nblocks];
    for (int i = r0 + t; i < r1; i += 256)
        atomicAdd(&ldeg[staged[i] >> 17], 1);
    __syncthreads();
    int gbase = b << NBSHIFT;
    #pragma unroll
    for (int k = 0; k < 2; ++k) {
        int li = t + k * 256, gi = gbase + li;
        if (gi < n) {
            int d = ldeg[li];
            deg[gi] = d;
            dis[gi] = rsqrtf((float)d + 1.0f);
        }
    }
}

// ---- per-bucket CSR fill with LDS cursors ----------------------------------
__global__ void __launch_bounds__(256) fill3_kernel(const unsigned* __restrict__ staged,
                                                    const int* __restrict__ phist,
                                                    const int* __restrict__ off,
                                                    int* __restrict__ srcl,
                                                    int nblocks, int n) {
    __shared__ int lcur[512];
    int b = blockIdx.x, t = threadIdx.x;
    int gbase = b << NBSHIFT;
    #pragma unroll
    for (int k = 0; k < 2; ++k) {
        int li = t + k * 256, gi = gbase + li;
        lcur[li] = (gi < n) ? off[gi] : 0;
    }
    __syncthreads();
    int r0 = phist[b * nblocks];
    int r1 = phist[(b + 1) * nblocks];
    for (int i = r0 + t; i < r1; i += 256) {
        unsigned rec = staged[i];
        int pos = atomicAdd(&lcur[rec >> 17], 1);
        srcl[pos] = (int)(rec & 0x1FFFFu);
    }
}

// ---- W fragment prep: bf16 hi/lo frags arranged frag-major -----------------
__global__ void __launch_bounds__(256) wprep_kernel(const float* __restrict__ W0,
                                                    const float* __restrict__ W1,
                                                    const float* __restrict__ W2,
                                                    const float* __restrict__ W3,
                                                    short* __restrict__ wf) {
    const float* Ws[4] = {W0, W1, W2, W3};
    int l = blockIdx.x;
    const float* Wg = Ws[l];
    int t = threadIdx.x;
    int lane = t & 63;
    int ct = t >> 6;
    #pragma unroll
    for (int kk = 0; kk < 2; ++kk) {
        #pragma unroll
        for (int e = 0; e < 8; ++e) {
            int k = kk * 32 + (lane >> 4) * 8 + e;
            int c = ct * 16 + (lane & 15);
            float w = Wg[k * 64 + c];
            unsigned short hi = f2bf(w);
            unsigned short lo = f2bf(w - bf2f(hi));
            size_t b = ((size_t)l * 4 + ct) * 2 + kk;
            wf[((b * 2 + 0) * 64 + lane) * 8 + e] = (short)hi;
            wf[((b * 2 + 1) * 64 + lane) * 8 + e] = (short)lo;
        }
    }
}

// ---- bf16 split helper -----------------------------------------------------
#define SPLIT8(vA, vB, H, L) { \
    float _f[8] = {vA.x, vA.y, vA.z, vA.w, vB.x, vB.y, vB.z, vB.w}; \
    _Pragma("unroll") \
    for (int _e = 0; _e < 8; ++_e) { \
        unsigned short _h = f2bf(_f[_e]); \
        H[_e] = (short)_h; \
        L[_e] = (short)f2bf(_f[_e] - bf2f(_h)); \
    } }

// ---- unroll-8 neighbor gather (16-lane quarter, float4 per lane) -----------
__device__ __forceinline__ float4 gather_row(const float4* __restrict__ gv,
                                             const int* __restrict__ srcl,
                                             int e, int e1, float4 s, int r) {
    while (e1 - e >= 8) {
        int i0 = srcl[e + 0], i1 = srcl[e + 1], i2 = srcl[e + 2], i3 = srcl[e + 3];
        int i4 = srcl[e + 4], i5 = srcl[e + 5], i6 = srcl[e + 6], i7 = srcl[e + 7];
        float4 a0 = gv[i0 * 16 + r], a1 = gv[i1 * 16 + r];
        float4 a2 = gv[i2 * 16 + r], a3 = gv[i3 * 16 + r];
        float4 a4 = gv[i4 * 16 + r], a5 = gv[i5 * 16 + r];
        float4 a6 = gv[i6 * 16 + r], a7 = gv[i7 * 16 + r];
        s.x += ((a0.x + a1.x) + (a2.x + a3.x)) + ((a4.x + a5.x) + (a6.x + a7.x));
        s.y += ((a0.y + a1.y) + (a2.y + a3.y)) + ((a4.y + a5.y) + (a6.y + a7.y));
        s.z += ((a0.z + a1.z) + (a2.z + a3.z)) + ((a4.z + a5.z) + (a6.z + a7.z));
        s.w += ((a0.w + a1.w) + (a2.w + a3.w)) + ((a4.w + a5.w) + (a6.w + a7.w));
        e += 8;
    }
    if (e1 - e >= 4) {
        int i0 = srcl[e + 0], i1 = srcl[e + 1], i2 = srcl[e + 2], i3 = srcl[e + 3];
        float4 a0 = gv[i0 * 16 + r], a1 = gv[i1 * 16 + r];
        float4 a2 = gv[i2 * 16 + r], a3 = gv[i3 * 16 + r];
        s.x += (a0.x + a1.x) + (a2.x + a3.x);
        s.y += (a0.y + a1.y) + (a2.y + a3.y);
        s.z += (a0.z + a1.z) + (a2.z + a3.z);
        s.w += (a0.w + a1.w) + (a2.w + a3.w);
        e += 4;
    }
    while (e < e1) {
        float4 a = gv[srcl[e] * 16 + r];
        s.x += a.x; s.y += a.y; s.z += a.z; s.w += a.w;
        ++e;
    }
    return s;
}

// ---- MFMA gemm (layer 0): g[n][d] = dis[n] * sum_k x[n][k] * W[k][d] -------
__global__ void __launch_bounds__(256) gemm2_kernel(const float* __restrict__ in,
                                                    const short* __restrict__ wf,
                                                    const float* __restrict__ dis,
                                                    float* __restrict__ g, int n) {
    int t = threadIdx.x;
    int lane = t & 63;
    int wave = t >> 6;
    int c = lane & 15;
    int g4 = lane >> 4;

    short8 Bh[4][2], Bl[4][2];
    #pragma unroll
    for (int ct = 0; ct < 4; ++ct) {
        #pragma unroll
        for (int kk = 0; kk < 2; ++kk) {
            int b = (ct * 2 + kk) * 2;
            Bh[ct][kk] = *(const short8*)(wf + ((size_t)(b + 0) * 64 + lane) * 8);
            Bl[ct][kk] = *(const short8*)(wf + ((size_t)(b + 1) * 64 + lane) * 8);
        }
    }

    int tile = blockIdx.x * 4 + wave;
    int base = tile * 16;
    if (base >= n) return;

    const float4* ap = (const float4*)(in + (size_t)(base + c) * 64 + g4 * 8);
    float4 v00 = ap[0], v01 = ap[1];
    float4 v10 = ap[8], v11 = ap[9];

    short8 Ah0, Al0, Ah1, Al1;
    SPLIT8(v00, v01, Ah0, Al0);
    SPLIT8(v10, v11, Ah1, Al1);

    f32x4 acc[4];
    #pragma unroll
    for (int ct = 0; ct < 4; ++ct) {
        f32x4 a = {0.f, 0.f, 0.f, 0.f};
        a = __builtin_amdgcn_mfma_f32_16x16x32_bf16(Ah0, Bh[ct][0], a, 0, 0, 0);
        a = __builtin_amdgcn_mfma_f32_16x16x32_bf16(Ah1, Bh[ct][1], a, 0, 0, 0);
        a = __builtin_amdgcn_mfma_f32_16x16x32_bf16(Al0, Bh[ct][0], a, 0, 0, 0);
        a = __builtin_amdgcn_mfma_f32_16x16x32_bf16(Al1, Bh[ct][1], a, 0, 0, 0);
        a = __builtin_amdgcn_mfma_f32_16x16x32_bf16(Ah0, Bl[ct][0], a, 0, 0, 0);
        a = __builtin_amdgcn_mfma_f32_16x16x32_bf16(Ah1, Bl[ct][1], a, 0, 0, 0);
        acc[ct] = a;
    }

    f32x4 dvv = *(const f32x4*)(dis + base + g4 * 4);
    #pragma unroll
    for (int ct = 0; ct < 4; ++ct) {
        #pragma unroll
        for (int r = 0; r < 4; ++r) {
            g[(size_t)(base + g4 * 4 + r) * 64 + ct * 16 + c] = dvv[r] * acc[ct][r];
        }
    }
}

// ---- fused: h_l = tanh(dis*(g self+neigh)+b) -> g_{l+1} = dis*(h @ W) ------
// 64 nodes per block: phase 1 agg into padded LDS, phase 2 MFMA from LDS.
__global__ void __launch_bounds__(256) fused_kernel(const float* __restrict__ g_in,
                                                    const float* __restrict__ dis,
                                                    const int* __restrict__ off,
                                                    const int* __restrict__ srcl,
                                                    const float* __restrict__ bias,
                                                    const short* __restrict__ wfn,
                                                    float* __restrict__ g_out, int n) {
    __shared__ float hs[64][68];           // +4 pad: 2-way bank alias only
    int t = threadIdx.x;
    int base = blockIdx.x * 64;
    int r = t & 15;
    int qq = t >> 4;                        // quarter 0..15
    const float4* gv = (const float4*)g_in;
    float4 b4 = ((const float4*)bias)[r];

    #pragma unroll
    for (int p = 0; p < 4; ++p) {
        int nl = p * 16 + qq;
        int node = base + nl;
        if (node < n) {
            float4 s = gv[(size_t)node * 16 + r];
            float4 sg = gather_row(gv, srcl, off[node], off[node + 1], s, r);
            float dn = dis[node];
            hs[nl][r * 4 + 0] = tanh_fast(fmaf(dn, sg.x, b4.x));
            hs[nl][r * 4 + 1] = tanh_fast(fmaf(dn, sg.y, b4.y));
            hs[nl][r * 4 + 2] = tanh_fast(fmaf(dn, sg.z, b4.z));
            hs[nl][r * 4 + 3] = tanh_fast(fmaf(dn, sg.w, b4.w));
        }
    }
    __syncthreads();

    // phase 2: wave w -> 16-node tile rows [w*16, w*16+16)
    int lane = t & 63;
    int wave = t >> 6;
    int c = lane & 15;
    int g4 = lane >> 4;
    int obase = base + wave * 16;
    if (obase >= n) return;

    short8 Bh[4][2], Bl[4][2];
    #pragma unroll
    for (int ct = 0; ct < 4; ++ct) {
        #pragma unroll
        for (int kk = 0; kk < 2; ++kk) {
            int b = (ct * 2 + kk) * 2;
            Bh[ct][kk] = *(const short8*)(wfn + ((size_t)(b + 0) * 64 + lane) * 8);
            Bl[ct][kk] = *(const short8*)(wfn + ((size_t)(b + 1) * 64 + lane) * 8);
        }
    }

    const float* hr = &hs[wave * 16 + c][0];
    float4 v00 = *(const float4*)(hr + g4 * 8);
    float4 v01 = *(const float4*)(hr + g4 * 8 + 4);
    float4 v10 = *(const float4*)(hr + g4 * 8 + 32);
    float4 v11 = *(const float4*)(hr + g4 * 8 + 36);

    short8 Ah0, Al0, Ah1, Al1;
    SPLIT8(v00, v01, Ah0, Al0);
    SPLIT8(v10, v11, Ah1, Al1);

    f32x4 acc[4];
    #pragma unroll
    for (int ct = 0; ct < 4; ++ct) {
        f32x4 a = {0.f, 0.f, 0.f, 0.f};
        a = __builtin_amdgcn_mfma_f32_16x16x32_bf16(Ah0, Bh[ct][0], a, 0, 0, 0);
        a = __builtin_amdgcn_mfma_f32_16x16x32_bf16(Ah1, Bh[ct][1], a, 0, 0, 0);
        a = __builtin_amdgcn_mfma_f32_16x16x32_bf16(Al0, Bh[ct][0], a, 0, 0, 0);
        a = __builtin_amdgcn_mfma_f32_16x16x32_bf16(Al1, Bh[ct][1], a, 0, 0, 0);
        a = __builtin_amdgcn_mfma_f32_16x16x32_bf16(Ah0, Bl[ct][0], a, 0, 0, 0);
        a = __builtin_amdgcn_mfma_f32_16x16x32_bf16(Ah1, Bl[ct][1], a, 0, 0, 0);
        acc[ct] = a;
    }

    f32x4 dvv = *(const f32x4*)(dis + obase + g4 * 4);
    #pragma unroll
    for (int ct = 0; ct < 4; ++ct) {
        #pragma unroll
        for (int rr = 0; rr < 4; ++rr) {
            g_out[(size_t)(obase + g4 * 4 + rr) * 64 + ct * 16 + c] = dvv[rr] * acc[ct][rr];
        }
    }
}

// ---- fused final: agg(layer 3) + out = h @ Wo + bo -------------------------
__global__ void __launch_bounds__(256) fused_final_kernel(const float* __restrict__ g_in,
                                                          const float* __restrict__ dis,
                                                          const int* __restrict__ off,
                                                          const int* __restrict__ srcl,
                                                          const float* __restrict__ bias,
                                                          const float* __restrict__ Wo,
                                                          const float* __restrict__ bo,
                                                          float* __restrict__ out, int n) {
    __shared__ float hs[64][68];
    __shared__ float Wl[1024];
    __shared__ float bl[16];
    int t = threadIdx.x;
    for (int i = t; i < 1024; i += 256) Wl[i] = Wo[i];
    if (t < 16) bl[t] = bo[t];

    int base = blockIdx.x * 64;
    int r = t & 15;
    int qq = t >> 4;
    const float4* gv = (const float4*)g_in;
    float4 b4 = ((const float4*)bias)[r];

    #pragma unroll
    for (int p = 0; p < 4; ++p) {
        int nl = p * 16 + qq;
        int node = base + nl;
        if (node < n) {
            float4 s = gv[(size_t)node * 16 + r];
            float4 sg = gather_row(gv, srcl, off[node], off[node + 1], s, r);
            float dn = dis[node];
            hs[nl][r * 4 + 0] = tanh_fast(fmaf(dn, sg.x, b4.x));
            hs[nl][r * 4 + 1] = tanh_fast(fmaf(dn, sg.y, b4.y));
            hs[nl][r * 4 + 2] = tanh_fast(fmaf(dn, sg.z, b4.z));
            hs[nl][r * 4 + 3] = tanh_fast(fmaf(dn, sg.w, b4.w));
        }
    }
    __syncthreads();

    int nsub = t >> 4;
    int j = t & 15;
    #pragma unroll
    for (int p = 0; p < 4; ++p) {
        int nl = p * 16 + nsub;
        int node = base + nl;
        if (node < n) {
            const float* hr = &hs[nl][0];
            float acc = bl[j];
            #pragma unroll
            for (int k = 0; k < 64; ++k) acc = fmaf(hr[k], Wl[k * 16 + j], acc);
            out[(size_t)node * 16 + j] = acc;
        }
    }
}

// ---------------------------------------------------------------------------
extern "C" void kernel_launch(void* const* d_in, const int* in_sizes, int n_in,
                              void* d_out, int out_size, void* d_ws, size_t ws_size,
                              hipStream_t stream) {
    const float* x     = (const float*)d_in[0];
    const int*   ei    = (const int*)d_in[1];   // (2, E) int32
    const float* W[4]  = {(const float*)d_in[2], (const float*)d_in[4],
                          (const float*)d_in[6], (const float*)d_in[8]};
    const float* B[4]  = {(const float*)d_in[3], (const float*)d_in[5],
                          (const float*)d_in[7], (const float*)d_in[9]};
    const float* Wo    = (const float*)d_in[10];
    const float* bo    = (const float*)d_in[11];
    float* out         = (float*)d_out;

    const int N = in_sizes[0] / 64;
    const int E = in_sizes[1] / 2;
    const int* srcp = ei;
    const int* dstp = ei + E;

    const int NB       = (N + (1 << NBSHIFT) - 1) >> NBSHIFT;  // 196
    const int nblocksP = (E + 4095) / 4096;                    // 245
    const int NH       = NB * nblocksP;

    char* w = (char*)d_ws;
    size_t o = 0;
    auto alloc = [&](size_t bytes) { void* p = w + o; o = (o + bytes + 255) & ~(size_t)255; return p; };
    float*    dis    = (float*)alloc((size_t)N * 4);
    int*      degi   = (int*)  alloc((size_t)N * 4);
    int*      off    = (int*)  alloc((size_t)(N + 1) * 4);
    int*      csum   = (int*)  alloc(4096);
    int*      srcl   = (int*)  alloc((size_t)E * 4);
    int*      hist   = (int*)  alloc((size_t)NH * 4);
    int*      phist  = (int*)  alloc((size_t)(NH + 1) * 4);
    short*    wf     = (short*)alloc((size_t)4 * 8192 * 2);   // 4 layers x 16KB
    float*    bufA   = (float*)alloc((size_t)N * 64 * 4);
    float*    bufB   = (float*)alloc((size_t)N * 64 * 4);
    unsigned* staged = (unsigned*)bufA;    // reuse (4MB < 25.6MB), consumed pre-gemm

    int nchN = (N + 1023) / 1024;
    int nchH = (NH + 1023) / 1024;

    wprep_kernel<<<4, 256, 0, stream>>>(W[0], W[1], W[2], W[3], wf);
    hist_kernel<<<nblocksP, 256, 0, stream>>>(dstp, hist, E, NB, nblocksP);
    scan1_kernel<<<nchH, 1024, 0, stream>>>(hist, phist, csum, NH);
    scan2_kernel<<<1, 1024, 0, stream>>>(csum, nchH);
    scan3_kernel<<<nchH, 1024, 0, stream>>>(phist, csum, NH, E);
    part_kernel<<<nblocksP, 256, 0, stream>>>(srcp, dstp, phist, staged, E, NB, nblocksP);
    bdeg_kernel<<<NB, 256, 0, stream>>>(staged, phist, degi, dis, nblocksP, N);
    scan1_kernel<<<nchN, 1024, 0, stream>>>(degi, off, csum, N);
    scan2_kernel<<<1, 1024, 0, stream>>>(csum, nchN);
    scan3_kernel<<<nchN, 1024, 0, stream>>>(off, csum, N, E);
    fill3_kernel<<<NB, 256, 0, stream>>>(staged, phist, off, srcl, nblocksP, N);

    int tiles     = (N + 15) / 16;
    int g2_blocks = (tiles + 3) / 4;
    int f_blocks  = (N + 63) / 64;

    gemm2_kernel<<<g2_blocks, 256, 0, stream>>>(x, wf, dis, bufA, N);
    fused_kernel<<<f_blocks, 256, 0, stream>>>(bufA, dis, off, srcl, B[0],
                                               wf + (size_t)1 * 8192, bufB, N);
    fused_kernel<<<f_blocks, 256, 0, stream>>>(bufB, dis, off, srcl, B[1],
                                               wf + (size_t)2 * 8192, bufA, N);
    fused_kernel<<<f_blocks, 256, 0, stream>>>(bufA, dis, off, srcl, B[2],
                                               wf + (size_t)3 * 8192, bufB, N);
    fused_final_kernel<<<f_blocks, 256, 0, stream>>>(bufB, dis, off, srcl, B[3],
                                                     Wo, bo, out, N);
}